// Round 5
// baseline (120.677 us; speedup 1.0000x reference)
//
#include <hip/hip_runtime.h>

// Disable FMA contraction so float rounding matches the numpy reference
// op-for-op (threshold compares at 0.5 and argmax ties depend on it).
#pragma clang fp contract(off)

#define BB 32     // batch
#define NN 100    // gt boxes per image
#define PP 8732   // priors
#define NBX 35    // col-role blocks along the prior axis (35*256 >= 8732)
#define NRB 25    // row-role blocks: 4 waves/block * 25 = 100 rows

// -------------------------------------------------------------------------
// k_match: one dispatch, two block roles (no cross-lane ops in hot loops).
//
// Col role (blockIdx.x < NBX): thread owns prior p of batch b.
//   Loop j over 100 gts (wave-uniform scalar loads + s_area LDS broadcast),
//   track argmax_j (strict > = first occurrence) -> m8 byte. Pure VALU.
//
// Row role (blockIdx.x >= NBX): WAVE owns gt row (b, j).
//   Lanes stride priors p = lane, lane+64, ...; keep a running
//   (iou<<32)|~p u64 key in registers (max key = max iou, min p on ties --
//   identical semantics to the verified s_part scheme). ONE 6-step u64
//   shuffle reduce per row (not per j!), lane 0 plain-stores gkey[b][j].
//   No atomics, no memset, single writer per element.
//
// IoU expressions are textually identical in both roles and to the prior
// verified kernel -> identical instruction sequences -> bit-exact.
// -------------------------------------------------------------------------
__global__ __launch_bounds__(256) void k_match(
    const float* __restrict__ gt,        // [B,N,4] xyxy
    const float* __restrict__ priors,    // [P,4] cxcywh
    unsigned long long* __restrict__ gkey,  // [B][N] final row keys
    unsigned char* __restrict__ m8)         // [B,P]: best_j | (bg?0x80:0)
{
    __shared__ float s_area[NN];   // col role only (400 B)

    const int b = blockIdx.y;
    const int t = threadIdx.x;
    const float4* __restrict__ gtb =
        reinterpret_cast<const float4*>(gt) + b * NN;

    if (blockIdx.x < NBX) {
        // ---------------- column role: best gt per prior ----------------
        const int p = blockIdx.x * 256 + t;
        const bool valid = p < PP;
        const int pc = valid ? p : (PP - 1);

        if (t < NN) {
            float4 g = gtb[t];                 // per-thread vector gather
            s_area[t] = (g.z - g.x) * (g.w - g.y);
        }

        const float4 pr = reinterpret_cast<const float4*>(priors)[pc];
        const float px1 = pr.x - pr.z * 0.5f;
        const float py1 = pr.y - pr.w * 0.5f;
        const float px2 = pr.x + pr.z * 0.5f;
        const float py2 = pr.y + pr.w * 0.5f;
        const float area_b = (px2 - px1) * (py2 - py1);

        float best_ov = -1.0f;
        int best_j = 0;

        __syncthreads();   // s_area ready

        #pragma unroll 4
        for (int j = 0; j < NN; ++j) {
            float4 g = gtb[j];                 // uniform -> SGPRs
            float area_a = s_area[j];          // broadcast ds_read
            float ltx = fmaxf(g.x, px1), lty = fmaxf(g.y, py1);
            float rbx = fminf(g.z, px2), rby = fminf(g.w, py2);
            float w = fmaxf(rbx - ltx, 0.0f), h = fmaxf(rby - lty, 0.0f);
            float inter = w * h;
            float iou = inter / (area_a + area_b - inter + 1e-6f);
            if (iou > best_ov) { best_ov = iou; best_j = j; }
        }

        if (valid) {
            m8[b * PP + p] =
                (unsigned char)(best_j | ((best_ov < 0.5f) ? 0x80 : 0));
        }
    } else {
        // ---------------- row role: best prior per gt ----------------
        const int wid = t >> 6;
        const int lane = t & 63;
        const int j = (blockIdx.x - NBX) * 4 + wid;    // 0..99

        const float4 g = gtb[j];                        // uniform -> SGPRs
        const float area_a = (g.z - g.x) * (g.w - g.y);

        unsigned long long best = 0ull;   // any real key beats 0

        for (int p = lane; p < PP; p += 64) {
            const float4 pr = reinterpret_cast<const float4*>(priors)[p];
            const float px1 = pr.x - pr.z * 0.5f;
            const float py1 = pr.y - pr.w * 0.5f;
            const float px2 = pr.x + pr.z * 0.5f;
            const float py2 = pr.y + pr.w * 0.5f;
            const float area_b = (px2 - px1) * (py2 - py1);
            float ltx = fmaxf(g.x, px1), lty = fmaxf(g.y, py1);
            float rbx = fminf(g.z, px2), rby = fminf(g.w, py2);
            float w = fmaxf(rbx - ltx, 0.0f), h = fmaxf(rby - lty, 0.0f);
            float inter = w * h;
            float iou = inter / (area_a + area_b - inter + 1e-6f);
            // iou >= 0 so uint order == float order; ~p -> min p on ties
            unsigned long long key =
                ((unsigned long long)__float_as_uint(iou) << 32) |
                (unsigned int)(~p);
            if (key > best) best = key;
        }

        // one u64 wave-max reduce per row (12 bpermutes total; negligible)
        #pragma unroll
        for (int d = 1; d < 64; d <<= 1) {
            unsigned long long o = __shfl_xor(best, d);
            if (o > best) best = o;
        }
        if (lane == 0) gkey[b * NN + j] = best;
    }
}

// -------------------------------------------------------------------------
// k_encode: read the final per-row key, scatter forced matches into LDS
// (max j = last-write-wins, matching the reference scatter), then encode.
// -------------------------------------------------------------------------
__global__ __launch_bounds__(256) void k_encode(
    const float* __restrict__ gt,        // [B,N,4]
    const int*   __restrict__ labels,    // [B,N]
    const float* __restrict__ priors,    // [P,4]
    const unsigned long long* __restrict__ gkey,  // [B][N]
    const unsigned char* __restrict__ m8,         // [B,P]
    float* __restrict__ loc_out,         // [B,P,4]
    float* __restrict__ conf_out)        // [B,P]
{
    __shared__ int s_forced[256];        // local p -> forced gt j (-1 none)

    const int b = blockIdx.y;
    const int t = threadIdx.x;
    const int p = blockIdx.x * 256 + t;

    s_forced[t] = -1;
    __syncthreads();
    if (t < NN) {
        unsigned long long best = gkey[b * NN + t];
        int kp = (int)~(unsigned int)(best & 0xFFFFFFFFull);
        int lp = kp - blockIdx.x * 256;
        if ((unsigned)lp < 256u) atomicMax(&s_forced[lp], t);
    }
    __syncthreads();

    if (p >= PP) return;
    const int forced_j = s_forced[t];

    const unsigned char m = m8[b * PP + p];
    const int j    = (forced_j >= 0) ? forced_j : (m & 0x7f);
    const int lab  = labels[b * NN + j];
    const int conf = (forced_j < 0 && (m & 0x80)) ? 0 : (lab + 1);

    const float4 pr = reinterpret_cast<const float4*>(priors)[p];
    const float4 g  = reinterpret_cast<const float4*>(gt)[b * NN + j];
    const float mcx = (g.x + g.z) * 0.5f;
    const float mcy = (g.y + g.w) * 0.5f;
    const float mw  = fmaxf(g.z - g.x, 1e-6f);
    const float mh  = fmaxf(g.w - g.y, 1e-6f);
    const float gcx = (mcx - pr.x) / (0.1f * pr.z);
    const float gcy = (mcy - pr.y) / (0.1f * pr.w);
    const float gw  = logf(mw / pr.z) / 0.2f;
    const float gh  = logf(mh / pr.w) / 0.2f;

    reinterpret_cast<float4*>(loc_out)[b * PP + p] =
        make_float4(gcx, gcy, gw, gh);
    conf_out[b * PP + p] = (float)conf;
}

extern "C" void kernel_launch(void* const* d_in, const int* in_sizes, int n_in,
                              void* d_out, int out_size, void* d_ws, size_t ws_size,
                              hipStream_t stream) {
    const float* gt     = (const float*)d_in[0];  // [32,100,4] f32
    const int*   labels = (const int*)  d_in[1];  // [32,100] i32
    const float* priors = (const float*)d_in[2];  // [8732,4] f32

    float* loc  = (float*)d_out;                         // [32,8732,4]
    float* conf = (float*)d_out + (size_t)BB * PP * 4;   // [32,8732]

    // workspace: gkey [32][100] u64 (25.6 KB) + m8 [32][8732] (279 KB)
    unsigned long long* gkey = (unsigned long long*)d_ws;
    unsigned char* m8 = (unsigned char*)d_ws + (size_t)BB * NN * 8;

    dim3 grid_m(NBX + NRB, BB);   // 35 col-role + 25 row-role blocks
    dim3 grid_e(NBX, BB);

    k_match<<<grid_m, 256, 0, stream>>>(gt, priors, gkey, m8);
    k_encode<<<grid_e, 256, 0, stream>>>(gt, labels, priors, gkey,
                                         m8, loc, conf);
}

// Round 6
// 111.779 us; speedup vs baseline: 1.0796x; 1.0796x over previous
//
#include <hip/hip_runtime.h>

// Disable FMA contraction so float rounding matches the numpy reference
// op-for-op (threshold compares at 0.5 and argmax ties depend on it).
#pragma clang fp contract(off)

#define BB 32     // batch
#define NN 100    // gt boxes per image
#define PP 8732   // priors
#define NBX 35    // blocks along the prior axis

// -------------------------------------------------------------------------
// Kernel 1: thread owns prior p of batch b. Single fused pass.
//  - Col reduce (best gt per prior): thread-local argmax over j -> m8 byte.
//  - Row reduce (best prior per gt): per-j WAVE max via 6-step DPP
//    (row_shr 1/2/4/8 + row_bcast 15/31) -- pure VALU, no LDS pipe, no
//    lgkmcnt (this was round-3's mistake: shfl_xor -> ds_bpermute chains
//    serialized on lgkmcnt). Result lands in lane 63 -> readlane ->
//    ballot(iou==max) -> ffs = min lane = min p tie-break.
//  - Lane 0 stores (iou<<32)|~p key to s_part[j][wave]; ONE barrier at the
//    end; t<100 merges 4 waves and plain-stores part[b][bx][j] (USE_PART)
//    or atomicMax (fallback). Same key semantics as the verified scheme.
//  - Out-of-range lanes compute the real IoU of prior PP-1: value-equal
//    duplicates sit at HIGHER lanes than the real p=8731 lane (ffs never
//    picks them) or carry smaller ~p keys (merge never picks them).
//  - Exact IEEE f32 division kept -> bit-identical decisions vs reference.
// -------------------------------------------------------------------------

// Wave64 max of nonneg f32 via DPP; valid in lane 63 only.
// bound_ctrl=true: invalid-source lanes read 0.0f (identity for iou >= 0).
#define DPP_MAX_STEP(v, ctrl)                                             \
    v = fmaxf(v, __int_as_float(__builtin_amdgcn_update_dpp(              \
            0, __float_as_int(v), (ctrl), 0xf, 0xf, true)))

template <bool USE_PART>
__global__ __launch_bounds__(256) void k_iou_pass(
    const float* __restrict__ gt,        // [B,N,4] xyxy
    const float* __restrict__ priors,    // [P,4] cxcywh
    unsigned long long* __restrict__ red,   // part [B][NBX][NN] or gkey [B][N]
    unsigned char* __restrict__ m8)         // [B,P]: best_j | (bg?0x80:0)
{
    __shared__ float s_area[NN];                   // 400 B
    __shared__ unsigned long long s_part[NN][5];   // 4 used + pad, 4 KB

    const int b = blockIdx.y;
    const int t = threadIdx.x;
    const int p = blockIdx.x * 256 + t;
    const bool valid = p < PP;
    const int pc = valid ? p : (PP - 1);

    // wave-uniform base: compiler scalarizes these loads (s_load_dwordx4)
    const float4* __restrict__ gtb =
        reinterpret_cast<const float4*>(gt) + b * NN;

    if (t < NN) {
        float4 g = gtb[t];                // per-thread gather here (vector)
        s_area[t] = (g.z - g.x) * (g.w - g.y);
    }

    const float4 pr = reinterpret_cast<const float4*>(priors)[pc];
    const float px1 = pr.x - pr.z * 0.5f;
    const float py1 = pr.y - pr.w * 0.5f;
    const float px2 = pr.x + pr.z * 0.5f;
    const float py2 = pr.y + pr.w * 0.5f;
    const float area_b = (px2 - px1) * (py2 - py1);

    float best_ov = -1.0f;
    int best_j = 0;

    const int wbase = blockIdx.x * 256 + (t & ~63);  // p of lane 0, this wave
    const int wid = t >> 6;
    const bool lane0 = (t & 63) == 0;

    __syncthreads();   // s_area ready

    #pragma unroll 4
    for (int j = 0; j < NN; ++j) {
        float4 g = gtb[j];                 // uniform -> SGPRs
        float area_a = s_area[j];          // broadcast ds_read
        float ltx = fmaxf(g.x, px1), lty = fmaxf(g.y, py1);
        float rbx = fminf(g.z, px2), rby = fminf(g.w, py2);
        float w = fmaxf(rbx - ltx, 0.0f), h = fmaxf(rby - lty, 0.0f);
        float inter = w * h;
        float iou = inter / (area_a + area_b - inter + 1e-6f);

        // column argmax (strict > = first occurrence over ascending j)
        if (iou > best_ov) { best_ov = iou; best_j = j; }

        // row reduce: wave max via DPP (VALU only), then min-lane-of-max
        float v = iou;
        DPP_MAX_STEP(v, 0x111);   // row_shr:1
        DPP_MAX_STEP(v, 0x112);   // row_shr:2
        DPP_MAX_STEP(v, 0x114);   // row_shr:4
        DPP_MAX_STEP(v, 0x118);   // row_shr:8
        DPP_MAX_STEP(v, 0x142);   // row_bcast:15
        DPP_MAX_STEP(v, 0x143);   // row_bcast:31
        const float wmax = __int_as_float(
            __builtin_amdgcn_readlane(__float_as_int(v), 63));
        unsigned long long win = __ballot(iou == wmax);
        int lmin = __ffsll((long long)win) - 1;   // min lane == min p
        if (lane0) {
            s_part[j][wid] =
                ((unsigned long long)__float_as_uint(wmax) << 32) |
                (unsigned int)(~(wbase + lmin));
        }
    }
    __syncthreads();   // s_part visible

    // merge 4 wave partials per gt; plain store (or atomic)
    if (t < NN) {
        unsigned long long best = s_part[t][0];
        #pragma unroll
        for (int w = 1; w < 4; ++w) {
            unsigned long long k = s_part[t][w];
            if (k > best) best = k;                   // ~p breaks iou ties
        }
        if (USE_PART) {
            red[((size_t)b * NBX + blockIdx.x) * NN + t] = best;
        } else {
            atomicMax(&red[b * NN + t], best);
        }
    }
    if (valid) {
        m8[b * PP + p] =
            (unsigned char)(best_j | ((best_ov < 0.5f) ? 0x80 : 0));
    }
}

// -------------------------------------------------------------------------
// Kernel 2: reduce the 35 per-block row keys (USE_PART) or read gkey,
// scatter forced matches into LDS (max j = last-write-wins, matching the
// reference scatter), then encode.
// -------------------------------------------------------------------------
template <bool USE_PART>
__global__ __launch_bounds__(256) void k_encode(
    const float* __restrict__ gt,        // [B,N,4]
    const int*   __restrict__ labels,    // [B,N]
    const float* __restrict__ priors,    // [P,4]
    const unsigned long long* __restrict__ red,   // part or gkey
    const unsigned char* __restrict__ m8,         // [B,P]
    float* __restrict__ loc_out,         // [B,P,4]
    float* __restrict__ conf_out)        // [B,P]
{
    __shared__ int s_forced[256];        // local p -> forced gt j (-1 none)

    const int b = blockIdx.y;
    const int t = threadIdx.x;
    const int p = blockIdx.x * 256 + t;

    s_forced[t] = -1;
    __syncthreads();
    if (t < NN) {
        unsigned long long best;
        if (USE_PART) {
            const unsigned long long* q = red + (size_t)b * NBX * NN + t;
            best = q[0];
            #pragma unroll 5
            for (int bx = 1; bx < NBX; ++bx) {
                unsigned long long k = q[(size_t)bx * NN];
                if (k > best) best = k;
            }
        } else {
            best = red[b * NN + t];
        }
        int kp = (int)~(unsigned int)(best & 0xFFFFFFFFull);
        int lp = kp - blockIdx.x * 256;
        if ((unsigned)lp < 256u) atomicMax(&s_forced[lp], t);
    }
    __syncthreads();

    if (p >= PP) return;
    const int forced_j = s_forced[t];

    const unsigned char m = m8[b * PP + p];
    const int j    = (forced_j >= 0) ? forced_j : (m & 0x7f);
    const int lab  = labels[b * NN + j];
    const int conf = (forced_j < 0 && (m & 0x80)) ? 0 : (lab + 1);

    const float4 pr = reinterpret_cast<const float4*>(priors)[p];
    const float4 g  = reinterpret_cast<const float4*>(gt)[b * NN + j];
    const float mcx = (g.x + g.z) * 0.5f;
    const float mcy = (g.y + g.w) * 0.5f;
    const float mw  = fmaxf(g.z - g.x, 1e-6f);
    const float mh  = fmaxf(g.w - g.y, 1e-6f);
    const float gcx = (mcx - pr.x) / (0.1f * pr.z);
    const float gcy = (mcy - pr.y) / (0.1f * pr.w);
    const float gw  = logf(mw / pr.z) / 0.2f;
    const float gh  = logf(mh / pr.w) / 0.2f;

    reinterpret_cast<float4*>(loc_out)[b * PP + p] =
        make_float4(gcx, gcy, gw, gh);
    conf_out[b * PP + p] = (float)conf;
}

extern "C" void kernel_launch(void* const* d_in, const int* in_sizes, int n_in,
                              void* d_out, int out_size, void* d_ws, size_t ws_size,
                              hipStream_t stream) {
    const float* gt     = (const float*)d_in[0];  // [32,100,4] f32
    const int*   labels = (const int*)  d_in[1];  // [32,100] i32
    const float* priors = (const float*)d_in[2];  // [8732,4] f32

    float* loc  = (float*)d_out;                         // [32,8732,4]
    float* conf = (float*)d_out + (size_t)BB * PP * 4;   // [32,8732]

    const size_t part_bytes = (size_t)BB * NBX * NN * 8;   // 896,000
    const size_t m8_bytes   = (size_t)BB * PP;             // 279,424
    dim3 grid(NBX, BB);

    if (ws_size >= part_bytes + m8_bytes) {
        // atomic-free path: per-block partial keys, no memset dispatch
        unsigned long long* part = (unsigned long long*)d_ws;
        unsigned char* m8 = (unsigned char*)d_ws + part_bytes;
        k_iou_pass<true><<<grid, 256, 0, stream>>>(gt, priors, part, m8);
        k_encode<true><<<grid, 256, 0, stream>>>(gt, labels, priors, part,
                                                 m8, loc, conf);
    } else {
        // fallback: gkey + atomicMax (needs zeroed keys)
        unsigned long long* gkey = (unsigned long long*)d_ws;        // [32,100]
        unsigned char* m8 = (unsigned char*)d_ws + (size_t)BB * NN * 8;
        hipMemsetAsync(gkey, 0, (size_t)BB * NN * 8, stream);
        k_iou_pass<false><<<grid, 256, 0, stream>>>(gt, priors, gkey, m8);
        k_encode<false><<<grid, 256, 0, stream>>>(gt, labels, priors, gkey,
                                                  m8, loc, conf);
    }
}

// Round 7
// 95.786 us; speedup vs baseline: 1.2599x; 1.1670x over previous
//
#include <hip/hip_runtime.h>

// Disable FMA contraction so float rounding matches the numpy reference
// op-for-op (threshold compares at 0.5 and argmax ties depend on it).
#pragma clang fp contract(off)

#define BB 32     // batch
#define NN 100    // gt boxes per image
#define PP 8732   // priors
#define BPB 128   // priors per block (j-split: 256 thr = 128 priors x 2 halves)
#define HALF 50   // gt boxes per j-half
#define CH 16     // j-chunk for the transposed row-max reduce
#define LDW2 129  // padded row stride (u32): bank spread, 2-way max (free)
#define NSEG 8    // 128 priors / 16 per segment
#define NBX 69    // blocks along the prior axis (69*128 >= 8732)
#define EBX 35    // k_encode blocks (256 priors each)

// -------------------------------------------------------------------------
// Kernel 1 (j-split): thread owns (prior pl, j-half h) of batch b.
//   Per-thread work halves vs the 256-prior variant (50 IoUs) and the
//   grid doubles (69x32 blocks, ~25 KB LDS -> 6 blocks/CU) -- both attack
//   the measured ~3x latency exposure (dur ~ 14 ns/instr at occ 29%).
//  - Column argmax: each half tracks strict-> argmax over its own 50 js
//    (ascending), then half1's (ov,j) merges into half0 via LDS with
//    strict > -- exactly sequential first-occurrence over j=0..99.
//  - Row max: round-1's chunk-transpose (cheapest measured per-j reduce):
//    s_iou[32 rows][128 cols] per chunk, phase A = 32 rows x 8 segs of 16,
//    key = (iou<<32)|~p (max iou, then min p), phase B merges 8 segs ->
//    plain store part[b][bx][j] (USE_PART) or atomicMax (fallback).
//  - Out-of-range lanes compute the real IoU of prior PP-1: duplicate
//    columns tie with p=8731's value and lose the ~p min-p tie-break.
//  - Exact IEEE f32 division kept -> bit-identical decisions vs reference.
// -------------------------------------------------------------------------
template <bool USE_PART>
__global__ __launch_bounds__(256) void k_iou_pass(
    const float* __restrict__ gt,        // [B,N,4] xyxy
    const float* __restrict__ priors,    // [P,4] cxcywh
    unsigned long long* __restrict__ red,   // part [B][NBX][NN] or gkey [B][N]
    unsigned char* __restrict__ m8)         // [B,P]: best_j | (bg?0x80:0)
{
    __shared__ unsigned int s_iou[2 * CH][LDW2];        // 16.5 KB
    __shared__ unsigned long long s_part[NN][NSEG + 1]; // 7.2 KB
    __shared__ float s_area[NN];                        // 400 B
    __shared__ unsigned long long s_cmerge[BPB];        // 1 KB

    const int b = blockIdx.y;
    const int t = threadIdx.x;
    const int h  = t >> 7;          // j-half (wave-uniform: waves 0,1 vs 2,3)
    const int pl = t & 127;         // local prior
    const int p = blockIdx.x * BPB + pl;
    const bool valid = p < PP;
    const int pc = valid ? p : (PP - 1);
    const int j0 = h * HALF;

    // wave-uniform base: compiler scalarizes these loads (s_load_dwordx4)
    const float4* __restrict__ gtb =
        reinterpret_cast<const float4*>(gt) + b * NN;

    if (t < NN) {
        float4 g = gtb[t];                // per-thread gather here (vector)
        s_area[t] = (g.z - g.x) * (g.w - g.y);
    }

    const float4 pr = reinterpret_cast<const float4*>(priors)[pc];
    const float px1 = pr.x - pr.z * 0.5f;
    const float py1 = pr.y - pr.w * 0.5f;
    const float px2 = pr.x + pr.z * 0.5f;
    const float py2 = pr.y + pr.w * 0.5f;
    const float area_b = (px2 - px1) * (py2 - py1);

    float best_ov = -1.0f;
    int best_j = 0;

    __syncthreads();   // s_area ready

    for (int jc = 0; jc < HALF; jc += CH) {
        const int nr = (HALF - jc) < CH ? (HALF - jc) : CH;

        #pragma unroll
        for (int jj = 0; jj < CH; ++jj) {
            if (jj >= nr) break;
            const int j = j0 + jc + jj;
            float4 g = gtb[j];                 // uniform -> SGPRs
            float area_a = s_area[j];          // broadcast ds_read
            float ltx = fmaxf(g.x, px1), lty = fmaxf(g.y, py1);
            float rbx = fminf(g.z, px2), rby = fminf(g.w, py2);
            float w = fmaxf(rbx - ltx, 0.0f), h2 = fmaxf(rby - lty, 0.0f);
            float inter = w * h2;
            float iou = inter / (area_a + area_b - inter + 1e-6f);
            if (iou > best_ov) { best_ov = iou; best_j = j; }
            s_iou[h * CH + jj][pl] = __float_as_uint(iou); // iou>=0: uint order
        }
        __syncthreads();

        // phase A: 32 rows (16 per half) x 8 segs of 16 ascending-p columns
        {
            const int r = t & 31;          // s_iou row
            const int s = t >> 5;          // segment 0..7
            const int rr = r & 15;         // jj within the half
            const int rh = r >> 4;         // which half's rows
            if (rr < nr) {
                const unsigned int* row = &s_iou[r][s * 16];
                unsigned int bb = row[0];
                int bi = 0;
                #pragma unroll
                for (int i = 1; i < 16; ++i) {
                    unsigned int v = row[i];
                    if (v > bb) { bb = v; bi = i; }   // strict > = min p
                }
                int pw = blockIdx.x * BPB + s * 16 + bi;
                s_part[rh * HALF + jc + rr][s] =
                    ((unsigned long long)bb << 32) | (unsigned int)(~pw);
            }
        }
        __syncthreads();   // s_iou reusable next chunk; s_part visible
    }

    // column merge: half1 -> half0 (strict >: lower j wins ties, matching
    // sequential first-occurrence since all half0 js < half1 js)
    if (h == 1) {
        s_cmerge[pl] = ((unsigned long long)__float_as_uint(best_ov) << 32) |
                       (unsigned int)best_j;
    }
    __syncthreads();

    if (h == 0) {
        unsigned long long k1 = s_cmerge[pl];
        float ov1 = __uint_as_float((unsigned int)(k1 >> 32));
        int   j1  = (int)(k1 & 0xFFFFFFFFull);
        if (ov1 > best_ov) { best_ov = ov1; best_j = j1; }
        if (valid) {
            m8[b * PP + p] =
                (unsigned char)(best_j | ((best_ov < 0.5f) ? 0x80 : 0));
        }
    }

    // phase B: merge 8 segment partials per gt; plain store (or atomic)
    if (t < NN) {
        unsigned long long best = s_part[t][0];
        #pragma unroll
        for (int s = 1; s < NSEG; ++s) {
            unsigned long long k = s_part[t][s];
            if (k > best) best = k;                   // ~p breaks iou ties
        }
        if (USE_PART) {
            red[((size_t)b * NBX + blockIdx.x) * NN + t] = best;
        } else {
            atomicMax(&red[b * NN + t], best);
        }
    }
}

// -------------------------------------------------------------------------
// Kernel 2: reduce the 69 per-block row keys (USE_PART) or read gkey,
// scatter forced matches into LDS (max j = last-write-wins, matching the
// reference scatter), then encode. 256 priors per block (35 blocks).
// -------------------------------------------------------------------------
template <bool USE_PART>
__global__ __launch_bounds__(256) void k_encode(
    const float* __restrict__ gt,        // [B,N,4]
    const int*   __restrict__ labels,    // [B,N]
    const float* __restrict__ priors,    // [P,4]
    const unsigned long long* __restrict__ red,   // part or gkey
    const unsigned char* __restrict__ m8,         // [B,P]
    float* __restrict__ loc_out,         // [B,P,4]
    float* __restrict__ conf_out)        // [B,P]
{
    __shared__ int s_forced[256];        // local p -> forced gt j (-1 none)

    const int b = blockIdx.y;
    const int t = threadIdx.x;
    const int p = blockIdx.x * 256 + t;

    s_forced[t] = -1;
    __syncthreads();
    if (t < NN) {
        unsigned long long best;
        if (USE_PART) {
            const unsigned long long* q = red + (size_t)b * NBX * NN + t;
            best = q[0];
            #pragma unroll 4
            for (int bx = 1; bx < NBX; ++bx) {
                unsigned long long k = q[(size_t)bx * NN];
                if (k > best) best = k;
            }
        } else {
            best = red[b * NN + t];
        }
        int kp = (int)~(unsigned int)(best & 0xFFFFFFFFull);
        int lp = kp - blockIdx.x * 256;
        if ((unsigned)lp < 256u) atomicMax(&s_forced[lp], t);
    }
    __syncthreads();

    if (p >= PP) return;
    const int forced_j = s_forced[t];

    const unsigned char m = m8[b * PP + p];
    const int j    = (forced_j >= 0) ? forced_j : (m & 0x7f);
    const int lab  = labels[b * NN + j];
    const int conf = (forced_j < 0 && (m & 0x80)) ? 0 : (lab + 1);

    const float4 pr = reinterpret_cast<const float4*>(priors)[p];
    const float4 g  = reinterpret_cast<const float4*>(gt)[b * NN + j];
    const float mcx = (g.x + g.z) * 0.5f;
    const float mcy = (g.y + g.w) * 0.5f;
    const float mw  = fmaxf(g.z - g.x, 1e-6f);
    const float mh  = fmaxf(g.w - g.y, 1e-6f);
    const float gcx = (mcx - pr.x) / (0.1f * pr.z);
    const float gcy = (mcy - pr.y) / (0.1f * pr.w);
    const float gw  = logf(mw / pr.z) / 0.2f;
    const float gh  = logf(mh / pr.w) / 0.2f;

    reinterpret_cast<float4*>(loc_out)[b * PP + p] =
        make_float4(gcx, gcy, gw, gh);
    conf_out[b * PP + p] = (float)conf;
}

extern "C" void kernel_launch(void* const* d_in, const int* in_sizes, int n_in,
                              void* d_out, int out_size, void* d_ws, size_t ws_size,
                              hipStream_t stream) {
    const float* gt     = (const float*)d_in[0];  // [32,100,4] f32
    const int*   labels = (const int*)  d_in[1];  // [32,100] i32
    const float* priors = (const float*)d_in[2];  // [8732,4] f32

    float* loc  = (float*)d_out;                         // [32,8732,4]
    float* conf = (float*)d_out + (size_t)BB * PP * 4;   // [32,8732]

    const size_t part_bytes = (size_t)BB * NBX * NN * 8;   // 1,766,400
    const size_t m8_bytes   = (size_t)BB * PP;             // 279,424
    dim3 grid_i(NBX, BB);
    dim3 grid_e(EBX, BB);

    if (ws_size >= part_bytes + m8_bytes) {
        // atomic-free path: per-block partial keys, no memset dispatch
        unsigned long long* part = (unsigned long long*)d_ws;
        unsigned char* m8 = (unsigned char*)d_ws + part_bytes;
        k_iou_pass<true><<<grid_i, 256, 0, stream>>>(gt, priors, part, m8);
        k_encode<true><<<grid_e, 256, 0, stream>>>(gt, labels, priors, part,
                                                   m8, loc, conf);
    } else {
        // fallback: gkey + atomicMax (needs zeroed keys)
        unsigned long long* gkey = (unsigned long long*)d_ws;        // [32,100]
        unsigned char* m8 = (unsigned char*)d_ws + (size_t)BB * NN * 8;
        hipMemsetAsync(gkey, 0, (size_t)BB * NN * 8, stream);
        k_iou_pass<false><<<grid_i, 256, 0, stream>>>(gt, priors, gkey, m8);
        k_encode<false><<<grid_e, 256, 0, stream>>>(gt, labels, priors, gkey,
                                                    m8, loc, conf);
    }
}